// Round 1
// baseline (1053.160 us; speedup 1.0000x reference)
//
#include <hip/hip_runtime.h>
#include <math.h>

#define B_ 4
#define T_ 200
#define U_ 100
#define V_ 1024
#define DE 144
#define DD 320
#define J_ 320

__device__ __forceinline__ float fast_tanh(float x) {
    // tanh(x) = 1 - 2/(exp(2x)+1); handles +-inf correctly
    float e = __expf(2.0f * x);
    return 1.0f - __fdividef(2.0f, e + 1.0f);
}

// ---------------------------------------------------------------------------
// Projection: Y[r][c] = sum_k X[r][k] * W[k][c] + bias[c]
// grid = rows, block = J_ (=320) threads. Input row staged in LDS.
// ---------------------------------------------------------------------------
template <int K>
__global__ __launch_bounds__(J_) void proj_kernel(const float* __restrict__ X,
                                                  const float* __restrict__ W,
                                                  const float* __restrict__ bias,
                                                  float* __restrict__ Y) {
    __shared__ float sx[K];
    const int r = blockIdx.x;
    const int c = threadIdx.x;  // 0..319
    for (int k = threadIdx.x; k < K; k += J_) sx[k] = X[r * K + k];
    __syncthreads();
    float acc = bias[c];
#pragma unroll 4
    for (int k = 0; k < K; k++) acc = fmaf(sx[k], W[k * J_ + c], acc);
    Y[r * J_ + c] = acc;
}

// ---------------------------------------------------------------------------
// Joint kernel: for 16 rows (flattened (b,t,u)) per block:
//   h = tanh(enc_p[b,t,:] + dec_p[b,u,:])           (J=320, staged in LDS)
//   logits = h @ W_out + b_out                      (V=1024)
//   lse = logsumexp(logits)
//   blank_lp[b,t,u] = logits[0] - lse
//   emit_lp[b,t,u]  = logits[targets[b,u]] - lse    (u < U)
// block = 256 threads; thread owns 4 consecutive cols (c0 = tid*4).
// ---------------------------------------------------------------------------
__global__ __launch_bounds__(256) void joint_kernel(
    const float* __restrict__ enc_p, const float* __restrict__ dec_p,
    const float* __restrict__ W_out, const float* __restrict__ b_out,
    const int* __restrict__ targets,
    float* __restrict__ blank_lp, float* __restrict__ emit_lp) {
    __shared__ __align__(16) float sh[16 * J_];
    __shared__ float red_m[4][16];
    __shared__ float red_s[4][16];
    __shared__ float lse_sh[16];

    const int r0 = blockIdx.x * 16;
    const int tid = threadIdx.x;

    // Phase 1: stage h = tanh(e + d) into LDS
    for (int idx = tid; idx < 16 * J_; idx += 256) {
        int i = idx / J_;
        int k = idx - i * J_;
        int r = r0 + i;
        int b = r / (T_ * (U_ + 1));
        int rem = r - b * (T_ * (U_ + 1));
        int t = rem / (U_ + 1);
        int u = rem - t * (U_ + 1);
        float e = enc_p[(b * T_ + t) * J_ + k];
        float d = dec_p[(b * (U_ + 1) + u) * J_ + k];
        sh[idx] = fast_tanh(e + d);
    }
    __syncthreads();

    const int c0 = tid * 4;
    float4 acc[16];
#pragma unroll
    for (int i = 0; i < 16; i++) acc[i] = make_float4(0.f, 0.f, 0.f, 0.f);

    for (int k = 0; k < J_; k += 4) {
        float4 w0 = *(const float4*)&W_out[(k + 0) * V_ + c0];
        float4 w1 = *(const float4*)&W_out[(k + 1) * V_ + c0];
        float4 w2 = *(const float4*)&W_out[(k + 2) * V_ + c0];
        float4 w3 = *(const float4*)&W_out[(k + 3) * V_ + c0];
#pragma unroll
        for (int i = 0; i < 16; i++) {
            float4 h4 = *(const float4*)&sh[i * J_ + k];
            float4 a = acc[i];
            a.x = fmaf(h4.x, w0.x, a.x); a.x = fmaf(h4.y, w1.x, a.x);
            a.x = fmaf(h4.z, w2.x, a.x); a.x = fmaf(h4.w, w3.x, a.x);
            a.y = fmaf(h4.x, w0.y, a.y); a.y = fmaf(h4.y, w1.y, a.y);
            a.y = fmaf(h4.z, w2.y, a.y); a.y = fmaf(h4.w, w3.y, a.y);
            a.z = fmaf(h4.x, w0.z, a.z); a.z = fmaf(h4.y, w1.z, a.z);
            a.z = fmaf(h4.z, w2.z, a.z); a.z = fmaf(h4.w, w3.z, a.z);
            a.w = fmaf(h4.x, w0.w, a.w); a.w = fmaf(h4.y, w1.w, a.w);
            a.w = fmaf(h4.z, w2.w, a.w); a.w = fmaf(h4.w, w3.w, a.w);
            acc[i] = a;
        }
    }

    // Epilogue: add bias, per-row logsumexp over 1024 cols (4/thread x 256 thr)
    float4 bo = *(const float4*)&b_out[c0];
    const int lane = tid & 63;
    const int wave = tid >> 6;
#pragma unroll
    for (int i = 0; i < 16; i++) {
        float l0 = acc[i].x + bo.x;
        float l1 = acc[i].y + bo.y;
        float l2 = acc[i].z + bo.z;
        float l3 = acc[i].w + bo.w;
        acc[i] = make_float4(l0, l1, l2, l3);
        float m = fmaxf(fmaxf(l0, l1), fmaxf(l2, l3));
        float s = __expf(l0 - m) + __expf(l1 - m) + __expf(l2 - m) + __expf(l3 - m);
#pragma unroll
        for (int off = 32; off > 0; off >>= 1) {
            float mo = __shfl_xor(m, off, 64);
            float so = __shfl_xor(s, off, 64);
            float M = fmaxf(m, mo);
            s = s * __expf(m - M) + so * __expf(mo - M);
            m = M;
        }
        if (lane == 0) { red_m[wave][i] = m; red_s[wave][i] = s; }
    }
    __syncthreads();
    if (tid < 16) {
        float m = red_m[0][tid];
        float s = red_s[0][tid];
#pragma unroll
        for (int w = 1; w < 4; w++) {
            float mo = red_m[w][tid], so = red_s[w][tid];
            float M = fmaxf(m, mo);
            s = s * __expf(m - M) + so * __expf(mo - M);
            m = M;
        }
        lse_sh[tid] = m + __logf(s);
    }
    __syncthreads();

#pragma unroll
    for (int i = 0; i < 16; i++) {
        int r = r0 + i;
        int b = r / (T_ * (U_ + 1));
        int rem = r - b * (T_ * (U_ + 1));
        int t = rem / (U_ + 1);
        int u = rem - t * (U_ + 1);
        float lse = lse_sh[i];
        if (c0 == 0) blank_lp[(b * T_ + t) * (U_ + 1) + u] = acc[i].x - lse;
        if (u < U_) {
            int tgt = targets[b * U_ + u];
            if (tgt >= c0 && tgt < c0 + 4) {
                float lv = (tgt == c0) ? acc[i].x
                         : (tgt == c0 + 1) ? acc[i].y
                         : (tgt == c0 + 2) ? acc[i].z
                         : acc[i].w;
                emit_lp[(b * T_ + t) * U_ + u] = lv - lse;
            }
        }
    }
}

// ---------------------------------------------------------------------------
// RNN-T alpha recursion, anti-diagonal wavefront. Single block, 512 threads.
// alpha[t][u] = logaddexp(alpha[t-1][u] + blank[t-1][u],
//                         alpha[t][u-1] + emit[t][u-1])
// alpha[0][u] = cumsum of emit[0][:u]; alpha[t][0] = alpha[t-1][0]+blank[t-1][0]
// ll[b] = alpha[el-1][tl] + blank[el-1][tl]; out = mean(-ll)
// ---------------------------------------------------------------------------
__global__ __launch_bounds__(512) void alpha_kernel(
    const float* __restrict__ blank_lp, const float* __restrict__ emit_lp,
    const int* __restrict__ enc_len, const int* __restrict__ tgt_len,
    float* __restrict__ out) {
    __shared__ float alpha[B_][128];
    __shared__ float ll[B_];
    const int tid = threadIdx.x;
    const int b = tid >> 7;
    const int u = tid & 127;
    const bool lane_ok = (u <= U_);
    const int el = enc_len[b];
    const int tl = tgt_len[b];

    for (int d = 0; d <= T_ + U_ - 2; d++) {
        const int t = d - u;
        const bool active = lane_ok && (t >= 0) && (t < T_);
        float val = 0.0f;
        if (active) {
            if (d == 0) {
                val = 0.0f;
            } else if (t == 0) {
                val = alpha[b][u - 1] + emit_lp[(b * T_ + 0) * U_ + (u - 1)];
            } else if (u == 0) {
                val = alpha[b][0] + blank_lp[(b * T_ + t - 1) * (U_ + 1)];
            } else {
                float va = alpha[b][u] + blank_lp[(b * T_ + t - 1) * (U_ + 1) + u];
                float vb = alpha[b][u - 1] + emit_lp[(b * T_ + t) * U_ + (u - 1)];
                float M = fmaxf(va, vb);
                val = M + log1pf(__expf(fminf(va, vb) - M));
            }
        }
        __syncthreads();
        if (active) {
            alpha[b][u] = val;
            if (t == el - 1 && u == tl)
                ll[b] = val + blank_lp[(b * T_ + t) * (U_ + 1) + u];
        }
        __syncthreads();
    }
    if (tid == 0) out[0] = -0.25f * (ll[0] + ll[1] + ll[2] + ll[3]);
}

extern "C" void kernel_launch(void* const* d_in, const int* in_sizes, int n_in,
                              void* d_out, int out_size, void* d_ws, size_t ws_size,
                              hipStream_t stream) {
    const float* enc_out = (const float*)d_in[0];
    const float* dec_out = (const float*)d_in[1];
    const float* W_enc = (const float*)d_in[2];
    const float* b_enc = (const float*)d_in[3];
    const float* W_dec = (const float*)d_in[4];
    const float* b_dec = (const float*)d_in[5];
    const float* W_out = (const float*)d_in[6];
    const float* b_out = (const float*)d_in[7];
    const int* targets = (const int*)d_in[8];
    const int* enc_len = (const int*)d_in[9];
    const int* tgt_len = (const int*)d_in[10];

    float* ws = (float*)d_ws;
    float* enc_p = ws;                              // B*T*J      = 256000
    float* dec_p = enc_p + B_ * T_ * J_;            // B*(U+1)*J  = 129280
    float* blank = dec_p + B_ * (U_ + 1) * J_;      // B*T*(U+1)  = 80800
    float* emit = blank + B_ * T_ * (U_ + 1);       // B*T*U      = 80000

    proj_kernel<DE><<<B_ * T_, J_, 0, stream>>>(enc_out, W_enc, b_enc, enc_p);
    proj_kernel<DD><<<B_ * (U_ + 1), J_, 0, stream>>>(dec_out, W_dec, b_dec, dec_p);

    joint_kernel<<<(B_ * T_ * (U_ + 1)) / 16, 256, 0, stream>>>(
        enc_p, dec_p, W_out, b_out, targets, blank, emit);

    alpha_kernel<<<1, 512, 0, stream>>>(blank, emit, enc_len, tgt_len, (float*)d_out);
}

// Round 2
// 262.490 us; speedup vs baseline: 4.0122x; 4.0122x over previous
//
#include <hip/hip_runtime.h>
#include <math.h>

#define B_ 4
#define T_ 200
#define U_ 100
#define V_ 1024
#define DE 144
#define DD 320
#define J_ 320
#define M_TOT (B_ * T_ * (U_ + 1))  // 80800
#define SSTR 328                    // LDS row stride (bf16 elems): +8 pad -> 2-way bank (free)
#define DSTR 104                    // skewed blank/emit row stride (floats)
#define NDIAG 300                   // t+u in [0, 299]

typedef __attribute__((ext_vector_type(8))) short bf16x8_t;
typedef __attribute__((ext_vector_type(4))) float f32x4_t;

__device__ __forceinline__ float fast_tanh(float x) {
    float e = __expf(2.0f * x);
    return 1.0f - __fdividef(2.0f, e + 1.0f);
}

__device__ __forceinline__ ushort f2bf(float x) {
    uint u = __float_as_uint(x);
    uint r = (u + 0x7FFFu + ((u >> 16) & 1u)) >> 16;
    return (ushort)r;
}

// ---------------------------------------------------------------------------
// fp32 projections (tiny): Y[r][c] = sum_k X[r][k]*W[k][c] + bias[c]
// ---------------------------------------------------------------------------
template <int K>
__global__ __launch_bounds__(J_) void proj_kernel(const float* __restrict__ X,
                                                  const float* __restrict__ W,
                                                  const float* __restrict__ bias,
                                                  float* __restrict__ Y) {
    __shared__ float sx[K];
    const int r = blockIdx.x;
    const int c = threadIdx.x;
    for (int k = threadIdx.x; k < K; k += J_) sx[k] = X[r * K + k];
    __syncthreads();
    float acc = bias[c];
#pragma unroll 4
    for (int k = 0; k < K; k++) acc = fmaf(sx[k], W[k * J_ + c], acc);
    Y[r * J_ + c] = acc;
}

// ---------------------------------------------------------------------------
// Convert W_out (f32 [320][1024]) to fragment-ordered bf16 so each B-frag
// load in the joint kernel is one contiguous 1KB dwordx4 per wave.
// frag index = (v/16)*10 + (k/32); within frag: lane = (v&15)|(((k>>3)&3)<<4),
// elem = k&7.  (matches mfma_f32_16x16x32_bf16 B layout)
// ---------------------------------------------------------------------------
__global__ __launch_bounds__(256) void wconv_kernel(const float* __restrict__ W,
                                                    ushort* __restrict__ Wt) {
    int idx = blockIdx.x * 256 + threadIdx.x;  // 327680 total
    int k = idx >> 10;
    int v = idx & 1023;
    ushort b = f2bf(W[idx]);
    int frag = (v >> 4) * 10 + (k >> 5);
    int lane = (v & 15) | (((k >> 3) & 3) << 4);
    int elem = k & 7;
    Wt[frag * 512 + lane * 8 + elem] = b;
}

// ---------------------------------------------------------------------------
// Joint kernel, bf16 MFMA. Block = 512 thr (8 waves). 64 rows x 1024 cols.
// Wave w owns cols [128w, 128w+128): 4 Mtiles x 8 Ntiles of 16x16x32 MFMA.
// Epilogue: bias + row LSE (in-reg -> shfl16 -> cross-wave LDS), then write
// blank/emit log-probs directly into skewed [b][t+u][u] layout.
// ---------------------------------------------------------------------------
__global__ __launch_bounds__(512, 2) void joint_mfma(
    const float* __restrict__ enc_p, const float* __restrict__ dec_p,
    const ushort* __restrict__ Wt, const float* __restrict__ b_out,
    const int* __restrict__ targets,
    float* __restrict__ bsk, float* __restrict__ esk) {
    __shared__ ushort sh[64 * SSTR];
    __shared__ float partm[8][64];
    __shared__ float parts[8][64];
    __shared__ float lse_sh[64];
    __shared__ int tgt_sh[64];

    const int tid = threadIdx.x;
    const int r0 = blockIdx.x * 64;

    // Stage h = tanh(enc_p + dec_p) as bf16 into LDS (64 rows x 320 k)
    for (int q = tid; q < 64 * 80; q += 512) {
        int i = q / 80;
        int kq = q - i * 80;
        int k0 = kq * 4;
        int rc = r0 + i;
        if (rc > M_TOT - 1) rc = M_TOT - 1;
        int b = rc / 20200;
        int rem = rc - b * 20200;
        int t = rem / 101;
        int u = rem - t * 101;
        float4 e = *(const float4*)&enc_p[(b * 200 + t) * 320 + k0];
        float4 dd = *(const float4*)&dec_p[(b * 101 + u) * 320 + k0];
        ushort4 pk;
        pk.x = f2bf(fast_tanh(e.x + dd.x));
        pk.y = f2bf(fast_tanh(e.y + dd.y));
        pk.z = f2bf(fast_tanh(e.z + dd.z));
        pk.w = f2bf(fast_tanh(e.w + dd.w));
        *(ushort4*)&sh[i * SSTR + k0] = pk;
    }
    if (tid < 64) {
        int rc = r0 + tid;
        int tg = -1;
        if (rc < M_TOT) {
            int b = rc / 20200;
            int rem = rc - b * 20200;
            int u = rem - (rem / 101) * 101;
            if (u < U_) tg = targets[b * U_ + u];
        }
        tgt_sh[tid] = tg;
    }
    __syncthreads();

    const int wave = tid >> 6;
    const int lane = tid & 63;
    const int lrow = lane & 15;
    const int lk = (lane >> 4) * 8;
    const int cb16 = wave * 8;  // col-tile base in 16-col units

    f32x4_t acc[4][8];
#pragma unroll
    for (int mt = 0; mt < 4; mt++)
#pragma unroll
        for (int nt = 0; nt < 8; nt++) acc[mt][nt] = (f32x4_t)(0.0f);

    for (int ks = 0; ks < 10; ks++) {
        bf16x8_t a[4];
#pragma unroll
        for (int mt = 0; mt < 4; mt++)
            a[mt] = *(const bf16x8_t*)&sh[(mt * 16 + lrow) * SSTR + ks * 32 + lk];
#pragma unroll
        for (int nt = 0; nt < 8; nt++) {
            bf16x8_t bfr = *(const bf16x8_t*)&Wt[(((cb16 + nt) * 10 + ks) << 9) + lane * 8];
#pragma unroll
            for (int mt = 0; mt < 4; mt++)
                acc[mt][nt] = __builtin_amdgcn_mfma_f32_16x16x32_bf16(a[mt], bfr, acc[mt][nt], 0, 0, 0);
        }
    }

    // Bias
    float bo[8];
#pragma unroll
    for (int nt = 0; nt < 8; nt++) bo[nt] = b_out[wave * 128 + nt * 16 + lrow];
#pragma unroll
    for (int mt = 0; mt < 4; mt++)
#pragma unroll
        for (int nt = 0; nt < 8; nt++) {
            acc[mt][nt].x += bo[nt];
            acc[mt][nt].y += bo[nt];
            acc[mt][nt].z += bo[nt];
            acc[mt][nt].w += bo[nt];
        }

    // Row LSE: per (mt, j) reduce over 8 ntiles then over 16 lanes (cols)
#pragma unroll
    for (int mt = 0; mt < 4; mt++) {
#pragma unroll
        for (int j = 0; j < 4; j++) {
            float m = acc[mt][0][j];
#pragma unroll
            for (int nt = 1; nt < 8; nt++) m = fmaxf(m, acc[mt][nt][j]);
            float s = 0.0f;
#pragma unroll
            for (int nt = 0; nt < 8; nt++) s += __expf(acc[mt][nt][j] - m);
#pragma unroll
            for (int off = 1; off < 16; off <<= 1) {
                float mo = __shfl_xor(m, off, 16);
                float so = __shfl_xor(s, off, 16);
                float M = fmaxf(m, mo);
                s = s * __expf(m - M) + so * __expf(mo - M);
                m = M;
            }
            if (lrow == 0) {
                int row = mt * 16 + (lane >> 4) * 4 + j;
                partm[wave][row] = m;
                parts[wave][row] = s;
            }
        }
    }
    __syncthreads();
    if (tid < 64) {
        float m = partm[0][tid];
        float s = parts[0][tid];
#pragma unroll
        for (int w = 1; w < 8; w++) {
            float mo = partm[w][tid], so = parts[w][tid];
            float M = fmaxf(m, mo);
            s = s * __expf(m - M) + so * __expf(mo - M);
            m = M;
        }
        lse_sh[tid] = m + __logf(s);
    }
    __syncthreads();

    // Write blank (col 0) and emit (target col) into skewed layout
#pragma unroll
    for (int mt = 0; mt < 4; mt++) {
#pragma unroll
        for (int j = 0; j < 4; j++) {
            int lr = mt * 16 + (lane >> 4) * 4 + j;
            int r = r0 + lr;
            if (r >= M_TOT) continue;
            int tc = tgt_sh[lr];
            bool isblank = (wave == 0) && (lrow == 0);
            bool isemit = (tc >= 0) && ((tc >> 7) == wave) && ((tc & 15) == lrow);
            if (isblank || isemit) {
                int b = r / 20200;
                int rem = r - b * 20200;
                int t = rem / 101;
                int u = rem - t * 101;
                float lse = lse_sh[lr];
                if (isblank)
                    bsk[(b * NDIAG + t + u) * DSTR + u] = acc[mt][0][j] - lse;
                if (isemit) {
                    int ntl = (tc >> 4) & 7;
                    float v = acc[mt][0][j];
#pragma unroll
                    for (int nt = 1; nt < 8; nt++)
                        if (nt == ntl) v = acc[mt][nt][j];
                    esk[(b * NDIAG + t + u) * DSTR + u] = v - lse;
                }
            }
        }
    }
}

// ---------------------------------------------------------------------------
// Alpha recursion over skewed arrays: diagonal d reads contiguous row d-1
// of bsk/esk; next row prefetched into registers to hide L2 latency.
// ---------------------------------------------------------------------------
__global__ __launch_bounds__(512) void alpha2_kernel(
    const float* __restrict__ bsk, const float* __restrict__ esk,
    const int* __restrict__ enc_len, const int* __restrict__ tgt_len,
    float* __restrict__ out) {
    __shared__ float alpha[B_][128];
    __shared__ float ll[B_];
    const int tid = threadIdx.x;
    const int b = tid >> 7;
    const int u = tid & 127;
    const bool lok = (u <= U_);
    const int el = enc_len[b];
    const int tl = tgt_len[b];

    if (u == 0) alpha[b][0] = 0.0f;
    float nb = lok ? bsk[(b * NDIAG + 0) * DSTR + u] : 0.0f;
    float ne = (lok && u >= 1) ? esk[(b * NDIAG + 0) * DSTR + (u - 1)] : 0.0f;
    __syncthreads();

    for (int d = 1; d <= 299; d++) {
        const float cb = nb, ce = ne;
        nb = lok ? bsk[(b * NDIAG + d) * DSTR + u] : 0.0f;
        ne = (lok && u >= 1) ? esk[(b * NDIAG + d) * DSTR + (u - 1)] : 0.0f;
        const int t = d - u;
        const bool active = lok && (t >= 0) && (t < T_);
        float val = 0.0f;
        if (active) {
            float va = (t >= 1) ? alpha[b][u] + cb : -INFINITY;
            float vb = (u >= 1) ? alpha[b][u - 1] + ce : -INFINITY;
            float M = fmaxf(va, vb);
            val = M + __logf(1.0f + __expf(fminf(va, vb) - M));
        }
        __syncthreads();
        if (active) {
            alpha[b][u] = val;
            if (t == el - 1 && u == tl) ll[b] = val + nb;
        }
        __syncthreads();
    }
    if (tid == 0) out[0] = -0.25f * (ll[0] + ll[1] + ll[2] + ll[3]);
}

extern "C" void kernel_launch(void* const* d_in, const int* in_sizes, int n_in,
                              void* d_out, int out_size, void* d_ws, size_t ws_size,
                              hipStream_t stream) {
    const float* enc_out = (const float*)d_in[0];
    const float* dec_out = (const float*)d_in[1];
    const float* W_enc = (const float*)d_in[2];
    const float* b_enc = (const float*)d_in[3];
    const float* W_dec = (const float*)d_in[4];
    const float* b_dec = (const float*)d_in[5];
    const float* W_out = (const float*)d_in[6];
    const float* b_out = (const float*)d_in[7];
    const int* targets = (const int*)d_in[8];
    const int* enc_len = (const int*)d_in[9];
    const int* tgt_len = (const int*)d_in[10];

    float* ws = (float*)d_ws;
    float* enc_p = ws;                          // B*T*J      = 256000 f32
    float* dec_p = enc_p + B_ * T_ * J_;        // B*101*J    = 129280 f32
    float* bsk = dec_p + B_ * (U_ + 1) * J_;    // 4*300*104  = 124800 f32
    float* esk = bsk + B_ * NDIAG * DSTR;       // 4*300*104  = 124800 f32
    ushort* Wt = (ushort*)(esk + B_ * NDIAG * DSTR);  // 327680 bf16

    proj_kernel<DE><<<B_ * T_, J_, 0, stream>>>(enc_out, W_enc, b_enc, enc_p);
    proj_kernel<DD><<<B_ * (U_ + 1), J_, 0, stream>>>(dec_out, W_dec, b_dec, dec_p);
    wconv_kernel<<<(J_ * V_) / 256, 256, 0, stream>>>(W_out, Wt);

    joint_mfma<<<(M_TOT + 63) / 64, 512, 0, stream>>>(
        enc_p, dec_p, Wt, b_out, targets, bsk, esk);

    alpha2_kernel<<<1, 512, 0, stream>>>(bsk, esk, enc_len, tgt_len, (float*)d_out);
}

// Round 3
// 236.988 us; speedup vs baseline: 4.4439x; 1.1076x over previous
//
#include <hip/hip_runtime.h>
#include <math.h>

#define B_ 4
#define T_ 200
#define U_ 100
#define V_ 1024
#define DE 144
#define DD 320
#define J_ 320
#define M_TOT (B_ * T_ * (U_ + 1))  // 80800
#define SSTR 328                    // LDS row stride (bf16 elems)
#define DSTR 104                    // skewed blank/emit row stride (floats)
#define NDIAG 300                   // t+u in [0, 299]

typedef __attribute__((ext_vector_type(8))) short bf16x8_t;
typedef __attribute__((ext_vector_type(4))) float f32x4_t;

__device__ __forceinline__ float fast_tanh(float x) {
    float e = __expf(2.0f * x);
    return 1.0f - __fdividef(2.0f, e + 1.0f);
}

__device__ __forceinline__ ushort f2bf(float x) {
    uint u = __float_as_uint(x);
    uint r = (u + 0x7FFFu + ((u >> 16) & 1u)) >> 16;
    return (ushort)r;
}

// ---------------------------------------------------------------------------
// fp32 projections (tiny)
// ---------------------------------------------------------------------------
template <int K>
__global__ __launch_bounds__(J_) void proj_kernel(const float* __restrict__ X,
                                                  const float* __restrict__ W,
                                                  const float* __restrict__ bias,
                                                  float* __restrict__ Y) {
    __shared__ float sx[K];
    const int r = blockIdx.x;
    const int c = threadIdx.x;
    for (int k = threadIdx.x; k < K; k += J_) sx[k] = X[r * K + k];
    __syncthreads();
    float acc = bias[c];
#pragma unroll 4
    for (int k = 0; k < K; k++) acc = fmaf(sx[k], W[k * J_ + c], acc);
    Y[r * J_ + c] = acc;
}

// ---------------------------------------------------------------------------
// W_out (f32 [320][1024]) -> fragment-ordered bf16.
// frag = (v/16)*10 + (k/32); lane = (v&15)|(((k>>3)&3)<<4); elem = k&7.
// ---------------------------------------------------------------------------
__global__ __launch_bounds__(256) void wconv_kernel(const float* __restrict__ W,
                                                    ushort* __restrict__ Wt) {
    int idx = blockIdx.x * 256 + threadIdx.x;
    int k = idx >> 10;
    int v = idx & 1023;
    ushort b = f2bf(W[idx]);
    int frag = (v >> 4) * 10 + (k >> 5);
    int lane = (v & 15) | (((k >> 3) & 3) << 4);
    int elem = k & 7;
    Wt[frag * 512 + lane * 8 + elem] = b;
}

// ---------------------------------------------------------------------------
// Joint kernel: 1024 thr (16 waves), 64 rows x 1024 cols per block.
// Wave w owns cols [64w, 64w+64): acc = 4 Mtiles x 4 Ntiles (64 VGPR).
// ---------------------------------------------------------------------------
__global__ __launch_bounds__(1024, 4) void joint_mfma(
    const float* __restrict__ enc_p, const float* __restrict__ dec_p,
    const ushort* __restrict__ Wt, const float* __restrict__ b_out,
    const int* __restrict__ targets,
    float* __restrict__ bsk, float* __restrict__ esk) {
    __shared__ ushort sh[64 * SSTR];
    __shared__ float partm[16][64];
    __shared__ float parts[16][64];
    __shared__ float lse_sh[64];
    __shared__ int tgt_sh[64];

    const int tid = threadIdx.x;
    const int r0 = blockIdx.x * 64;

    // Stage h = tanh(enc_p + dec_p) as bf16 into LDS (64 rows x 320)
    for (int q = tid; q < 64 * 80; q += 1024) {
        int i = q / 80;
        int kq = q - i * 80;
        int k0 = kq * 4;
        int rc = r0 + i;
        if (rc > M_TOT - 1) rc = M_TOT - 1;
        int b = rc / 20200;
        int rem = rc - b * 20200;
        int t = rem / 101;
        int u = rem - t * 101;
        float4 e = *(const float4*)&enc_p[(b * 200 + t) * 320 + k0];
        float4 dd = *(const float4*)&dec_p[(b * 101 + u) * 320 + k0];
        ushort4 pk;
        pk.x = f2bf(fast_tanh(e.x + dd.x));
        pk.y = f2bf(fast_tanh(e.y + dd.y));
        pk.z = f2bf(fast_tanh(e.z + dd.z));
        pk.w = f2bf(fast_tanh(e.w + dd.w));
        *(ushort4*)&sh[i * SSTR + k0] = pk;
    }
    if (tid < 64) {
        int rc = r0 + tid;
        int tg = -1;
        if (rc < M_TOT) {
            int b = rc / 20200;
            int rem = rc - b * 20200;
            int u = rem - (rem / 101) * 101;
            if (u < U_) tg = targets[b * U_ + u];
        }
        tgt_sh[tid] = tg;
    }
    __syncthreads();

    const int wave = tid >> 6;   // 0..15
    const int lane = tid & 63;
    const int lrow = lane & 15;
    const int lk = (lane >> 4) * 8;
    const int cb16 = wave * 4;   // col-tile base in 16-col units

    f32x4_t acc[4][4];
#pragma unroll
    for (int mt = 0; mt < 4; mt++)
#pragma unroll
        for (int nt = 0; nt < 4; nt++) acc[mt][nt] = (f32x4_t)(0.0f);

    for (int ks = 0; ks < 10; ks++) {
        bf16x8_t a[4];
#pragma unroll
        for (int mt = 0; mt < 4; mt++)
            a[mt] = *(const bf16x8_t*)&sh[(mt * 16 + lrow) * SSTR + ks * 32 + lk];
#pragma unroll
        for (int nt = 0; nt < 4; nt++) {
            bf16x8_t bfr = *(const bf16x8_t*)&Wt[(((cb16 + nt) * 10 + ks) << 9) + lane * 8];
#pragma unroll
            for (int mt = 0; mt < 4; mt++)
                acc[mt][nt] = __builtin_amdgcn_mfma_f32_16x16x32_bf16(a[mt], bfr, acc[mt][nt], 0, 0, 0);
        }
    }

    // Bias
    float bo[4];
#pragma unroll
    for (int nt = 0; nt < 4; nt++) bo[nt] = b_out[wave * 64 + nt * 16 + lrow];
#pragma unroll
    for (int mt = 0; mt < 4; mt++)
#pragma unroll
        for (int nt = 0; nt < 4; nt++) {
            acc[mt][nt].x += bo[nt];
            acc[mt][nt].y += bo[nt];
            acc[mt][nt].z += bo[nt];
            acc[mt][nt].w += bo[nt];
        }

    // Row LSE: reduce over 4 ntiles then over 16 lanes (cols)
#pragma unroll
    for (int mt = 0; mt < 4; mt++) {
#pragma unroll
        for (int j = 0; j < 4; j++) {
            float m = acc[mt][0][j];
#pragma unroll
            for (int nt = 1; nt < 4; nt++) m = fmaxf(m, acc[mt][nt][j]);
            float s = 0.0f;
#pragma unroll
            for (int nt = 0; nt < 4; nt++) s += __expf(acc[mt][nt][j] - m);
#pragma unroll
            for (int off = 1; off < 16; off <<= 1) {
                float mo = __shfl_xor(m, off, 16);
                float so = __shfl_xor(s, off, 16);
                float M = fmaxf(m, mo);
                s = s * __expf(m - M) + so * __expf(mo - M);
                m = M;
            }
            if (lrow == 0) {
                int row = mt * 16 + (lane >> 4) * 4 + j;
                partm[wave][row] = m;
                parts[wave][row] = s;
            }
        }
    }
    __syncthreads();
    if (tid < 64) {
        float m = partm[0][tid];
        float s = parts[0][tid];
#pragma unroll
        for (int w = 1; w < 16; w++) {
            float mo = partm[w][tid], so = parts[w][tid];
            float M = fmaxf(m, mo);
            s = s * __expf(m - M) + so * __expf(mo - M);
            m = M;
        }
        lse_sh[tid] = m + __logf(s);
    }
    __syncthreads();

    // Write blank (col 0) and emit (target col) into skewed layout
#pragma unroll
    for (int mt = 0; mt < 4; mt++) {
#pragma unroll
        for (int j = 0; j < 4; j++) {
            int lr = mt * 16 + (lane >> 4) * 4 + j;
            int r = r0 + lr;
            if (r >= M_TOT) continue;
            int tc = tgt_sh[lr];
            bool isblank = (wave == 0) && (lrow == 0);
            bool isemit = (tc >= 0) && ((tc >> 6) == wave) && ((tc & 15) == lrow);
            if (isblank || isemit) {
                int b = r / 20200;
                int rem = r - b * 20200;
                int t = rem / 101;
                int u = rem - t * 101;
                float lse = lse_sh[lr];
                if (isblank)
                    bsk[(b * NDIAG + t + u) * DSTR + u] = acc[mt][0][j] - lse;
                if (isemit) {
                    int ntl = (tc >> 4) & 3;
                    float v = acc[mt][0][j];
#pragma unroll
                    for (int nt = 1; nt < 4; nt++)
                        if (nt == ntl) v = acc[mt][nt][j];
                    esk[(b * NDIAG + t + u) * DSTR + u] = v - lse;
                }
            }
        }
    }
}

// ---------------------------------------------------------------------------
// Alpha recursion: one wave per batch, barrier-free.
// Lane l holds u1=l and u2=64+l (valid l<=36). u-1 deps via shfl_up(1);
// the u=64 seam via broadcast of lane 63. 2-deep register prefetch of the
// skewed blank/emit rows hides L2 latency.
// ---------------------------------------------------------------------------
__global__ __launch_bounds__(256) void alpha3_kernel(
    const float* __restrict__ bsk, const float* __restrict__ esk,
    const int* __restrict__ enc_len, const int* __restrict__ tgt_len,
    float* __restrict__ out) {
    __shared__ float ll_sh[B_];
    const int tid = threadIdx.x;
    const int b = tid >> 6;
    const int l = tid & 63;
    const float* Bp = bsk + b * (NDIAG * DSTR);
    const float* Ep = esk + b * (NDIAG * DSTR);
    const int el = enc_len[b];
    const int tl = tgt_len[b];
    const int dfin = el - 1 + tl;

    float a1 = (l == 0) ? 0.0f : -INFINITY;  // alpha at diag d-1, u=l
    float a2 = -INFINITY;                    // alpha at diag d-1, u=64+l

    // rolling rows: c_* = row d-1 (consumed), m_* = row d, n_* = row d+1
    float c_b1 = Bp[l], c_b2 = Bp[64 + l];
    float c_e1 = Ep[l], c_e2 = Ep[64 + l];
    float m_b1 = Bp[DSTR + l], m_b2 = Bp[DSTR + 64 + l];
    float m_e1 = Ep[DSTR + l], m_e2 = Ep[DSTR + 64 + l];

    for (int d = 1; d <= NDIAG - 1; d++) {
        const int dn = (d + 1 <= NDIAG - 1) ? d + 1 : NDIAG - 1;
        float n_b1 = Bp[dn * DSTR + l], n_b2 = Bp[dn * DSTR + 64 + l];
        float n_e1 = Ep[dn * DSTR + l], n_e2 = Ep[dn * DSTR + 64 + l];

        float ce1 = __shfl_up(c_e1, 1, 64);
        float e1hi = __shfl(c_e1, 63, 64);
        float ce2s = __shfl_up(c_e2, 1, 64);
        float ce2 = (l == 0) ? e1hi : ce2s;
        float pa1 = __shfl_up(a1, 1, 64);
        float a1hi = __shfl(a1, 63, 64);
        float pa2s = __shfl_up(a2, 1, 64);
        float pa2 = (l == 0) ? a1hi : pa2s;

        const int t1 = d - l;
        float va = a1 + c_b1;
        float vb = (l >= 1) ? pa1 + ce1 : -INFINITY;
        float M = fmaxf(va, vb);
        float v1 = (M == -INFINITY) ? -INFINITY
                                    : M + __logf(1.0f + __expf(fminf(va, vb) - M));
        if (t1 < 0 || t1 >= T_ || l > U_) v1 = -INFINITY;

        const int t2 = d - 64 - l;
        float va2 = a2 + c_b2;
        float vb2 = pa2 + ce2;
        float M2 = fmaxf(va2, vb2);
        float v2 = (M2 == -INFINITY) ? -INFINITY
                                     : M2 + __logf(1.0f + __expf(fminf(va2, vb2) - M2));
        if (t2 < 0 || t2 >= T_ || (64 + l) > U_) v2 = -INFINITY;

        if (d == dfin) {
            if (l == tl) ll_sh[b] = v1 + m_b1;
            if (64 + l == tl) ll_sh[b] = v2 + m_b2;
        }

        a1 = v1; a2 = v2;
        c_b1 = m_b1; c_b2 = m_b2; c_e1 = m_e1; c_e2 = m_e2;
        m_b1 = n_b1; m_b2 = n_b2; m_e1 = n_e1; m_e2 = n_e2;
    }
    __syncthreads();
    if (tid == 0)
        out[0] = -0.25f * (ll_sh[0] + ll_sh[1] + ll_sh[2] + ll_sh[3]);
}

extern "C" void kernel_launch(void* const* d_in, const int* in_sizes, int n_in,
                              void* d_out, int out_size, void* d_ws, size_t ws_size,
                              hipStream_t stream) {
    const float* enc_out = (const float*)d_in[0];
    const float* dec_out = (const float*)d_in[1];
    const float* W_enc = (const float*)d_in[2];
    const float* b_enc = (const float*)d_in[3];
    const float* W_dec = (const float*)d_in[4];
    const float* b_dec = (const float*)d_in[5];
    const float* W_out = (const float*)d_in[6];
    const float* b_out = (const float*)d_in[7];
    const int* targets = (const int*)d_in[8];
    const int* enc_len = (const int*)d_in[9];
    const int* tgt_len = (const int*)d_in[10];

    float* ws = (float*)d_ws;
    float* enc_p = ws;                          // B*T*J      = 256000 f32
    float* dec_p = enc_p + B_ * T_ * J_;        // B*101*J    = 129280 f32
    float* bsk = dec_p + B_ * (U_ + 1) * J_;    // 4*300*104  = 124800 f32
    float* esk = bsk + B_ * NDIAG * DSTR;       // 4*300*104  = 124800 f32
    ushort* Wt = (ushort*)(esk + B_ * NDIAG * DSTR);  // 327680 bf16

    proj_kernel<DE><<<B_ * T_, J_, 0, stream>>>(enc_out, W_enc, b_enc, enc_p);
    proj_kernel<DD><<<B_ * (U_ + 1), J_, 0, stream>>>(dec_out, W_dec, b_dec, dec_p);
    wconv_kernel<<<(J_ * V_) / 256, 256, 0, stream>>>(W_out, Wt);

    joint_mfma<<<(M_TOT + 63) / 64, 1024, 0, stream>>>(
        enc_p, dec_p, Wt, b_out, targets, bsk, esk);

    alpha3_kernel<<<1, 256, 0, stream>>>(bsk, esk, enc_len, tgt_len, (float*)d_out);
}

// Round 4
// 218.036 us; speedup vs baseline: 4.8302x; 1.0869x over previous
//
#include <hip/hip_runtime.h>
#include <hip/hip_bf16.h>
#include <math.h>

#define B_ 4
#define T_ 200
#define U_ 100
#define V_ 1024
#define DE 144
#define DD 320
#define J_ 320
#define M_TOT (B_ * T_ * (U_ + 1))  // 80800
#define SSTR 328                    // LDS row stride (bf16 elems)
#define DSTR 104                    // skewed blank/emit row stride (floats)
#define NDIAG 300                   // t+u in [0, 299]
#define LOG2E 1.4426950408889634f

typedef __attribute__((ext_vector_type(8))) short bf16x8_t;
typedef __attribute__((ext_vector_type(4))) float f32x4_t;

__device__ __forceinline__ float fast_tanh(float x) {
    // tanh(x) = 1 - 2/(e^{2x}+1);  e^{2x} = 2^{x * 2*log2(e)}
    float e = exp2f(x * (2.0f * LOG2E));
    float r = __frcp_rn(e + 1.0f);
    return fmaf(-2.0f, r, 1.0f);
}

__device__ __forceinline__ ushort f2bf(float x) {
    uint u = __float_as_uint(x);
    uint r = (u + 0x7FFFu + ((u >> 16) & 1u)) >> 16;
    return (ushort)r;
}

// ---------------------------------------------------------------------------
// Fused prep: proj_enc (blocks 0..799), proj_dec (800..1203), wconv (1204..2227)
// ---------------------------------------------------------------------------
__global__ __launch_bounds__(320) void prep_kernel(
    const float* __restrict__ enc_out, const float* __restrict__ dec_out,
    const float* __restrict__ W_enc, const float* __restrict__ b_enc,
    const float* __restrict__ W_dec, const float* __restrict__ b_dec,
    const float* __restrict__ W_out,
    float* __restrict__ enc_p, float* __restrict__ dec_p,
    ushort* __restrict__ Wt) {
    const int bid = blockIdx.x;
    const int tid = threadIdx.x;
    if (bid < 1204) {
        __shared__ float sx[320];
        const float* X; const float* W; const float* bias; float* Y;
        int K, r;
        if (bid < 800) { X = enc_out; W = W_enc; bias = b_enc; Y = enc_p; K = DE; r = bid; }
        else           { X = dec_out; W = W_dec; bias = b_dec; Y = dec_p; K = DD; r = bid - 800; }
        for (int k = tid; k < K; k += 320) sx[k] = X[r * K + k];
        __syncthreads();
        float acc = bias[tid];
#pragma unroll 4
        for (int k = 0; k < K; k++) acc = fmaf(sx[k], W[k * J_ + tid], acc);
        Y[r * J_ + tid] = acc;
    } else {
        // W_out (f32 [320][1024]) -> fragment-ordered bf16.
        // frag = (v/16)*10 + (k/32); lane = (v&15)|(((k>>3)&3)<<4); elem = k&7
        int idx = (bid - 1204) * 320 + tid;  // 0..327679
        int k = idx >> 10;
        int v = idx & 1023;
        ushort b = f2bf(W_out[idx]);
        int frag = (v >> 4) * 10 + (k >> 5);
        int lane = (v & 15) | (((k >> 3) & 3) << 4);
        int elem = k & 7;
        Wt[frag * 512 + lane * 8 + elem] = b;
    }
}

// ---------------------------------------------------------------------------
// Joint kernel: 1024 thr (16 waves), 64 rows x 1024 cols per block.
// Wave w owns cols [64w, 64w+64): acc = 4 Mtiles x 4 Ntiles.
// ---------------------------------------------------------------------------
__global__ __launch_bounds__(1024, 4) void joint_mfma(
    const float* __restrict__ enc_p, const float* __restrict__ dec_p,
    const ushort* __restrict__ Wt, const float* __restrict__ b_out,
    const int* __restrict__ targets,
    float* __restrict__ bsk, float* __restrict__ esk) {
    __shared__ ushort sh[64 * SSTR];
    __shared__ float partm[16][64];
    __shared__ float parts[16][64];
    __shared__ float lse_sh[64];
    __shared__ int tgt_sh[64];

    const int tid = threadIdx.x;
    const int r0 = blockIdx.x * 64;

    // Stage h = tanh(enc_p + dec_p) as bf16 into LDS. Thread owns row si,
    // quads sq, sq+16, ..., sq+64 (5 iters); row addressing hoisted.
    {
        const int si = tid >> 4;       // 0..63
        const int sq = tid & 15;       // quad group
        int rc = r0 + si;
        if (rc > M_TOT - 1) rc = M_TOT - 1;
        int b = rc / 20200;
        int rem = rc - b * 20200;
        int t = rem / 101;
        int u = rem - t * 101;
        const float4* ep = (const float4*)&enc_p[(b * 200 + t) * 320];
        const float4* dp = (const float4*)&dec_p[(b * 101 + u) * 320];
        ushort* shp = &sh[si * SSTR];
#pragma unroll
        for (int it = 0; it < 5; it++) {
            int kq = sq + it * 16;     // 0..79
            float4 e = ep[kq];
            float4 dd = dp[kq];
            float t0 = fast_tanh(e.x + dd.x);
            float t1 = fast_tanh(e.y + dd.y);
            float t2 = fast_tanh(e.z + dd.z);
            float t3 = fast_tanh(e.w + dd.w);
            __hip_bfloat162 p0 = __float22bfloat162_rn(make_float2(t0, t1));
            __hip_bfloat162 p1 = __float22bfloat162_rn(make_float2(t2, t3));
            uint2 pk;
            pk.x = *(uint*)&p0;
            pk.y = *(uint*)&p1;
            *(uint2*)&shp[kq * 4] = pk;
        }
    }
    if (tid < 64) {
        int rc = r0 + tid;
        int tg = -1;
        if (rc < M_TOT) {
            int b = rc / 20200;
            int rem = rc - b * 20200;
            int u = rem - (rem / 101) * 101;
            if (u < U_) tg = targets[b * U_ + u];
        }
        tgt_sh[tid] = tg;
    }
    __syncthreads();

    const int wave = tid >> 6;   // 0..15
    const int lane = tid & 63;
    const int lrow = lane & 15;
    const int lk = (lane >> 4) * 8;
    const int cb16 = wave * 4;   // col-tile base in 16-col units

    f32x4_t acc[4][4];
#pragma unroll
    for (int mt = 0; mt < 4; mt++)
#pragma unroll
        for (int nt = 0; nt < 4; nt++) acc[mt][nt] = (f32x4_t)(0.0f);

    for (int ks = 0; ks < 10; ks++) {
        bf16x8_t a[4];
#pragma unroll
        for (int mt = 0; mt < 4; mt++)
            a[mt] = *(const bf16x8_t*)&sh[(mt * 16 + lrow) * SSTR + ks * 32 + lk];
#pragma unroll
        for (int nt = 0; nt < 4; nt++) {
            bf16x8_t bfr = *(const bf16x8_t*)&Wt[(((cb16 + nt) * 10 + ks) << 9) + lane * 8];
#pragma unroll
            for (int mt = 0; mt < 4; mt++)
                acc[mt][nt] = __builtin_amdgcn_mfma_f32_16x16x32_bf16(a[mt], bfr, acc[mt][nt], 0, 0, 0);
        }
    }

    // Bias
    float bo[4];
#pragma unroll
    for (int nt = 0; nt < 4; nt++) bo[nt] = b_out[wave * 64 + nt * 16 + lrow];
#pragma unroll
    for (int mt = 0; mt < 4; mt++)
#pragma unroll
        for (int nt = 0; nt < 4; nt++) acc[mt][nt] += bo[nt];

    // Row LSE, two-pass: (A) pure-fmax reduce over nt + 16 lanes,
    // (B) exp2-based sum with the wave-slice max, pure-add reduce.
#pragma unroll
    for (int mt = 0; mt < 4; mt++) {
#pragma unroll
        for (int j = 0; j < 4; j++) {
            float m = fmaxf(fmaxf(acc[mt][0][j], acc[mt][1][j]),
                            fmaxf(acc[mt][2][j], acc[mt][3][j]));
#pragma unroll
            for (int off = 1; off < 16; off <<= 1)
                m = fmaxf(m, __shfl_xor(m, off, 16));
            float mm = m * LOG2E;
            float s = exp2f(fmaf(acc[mt][0][j], LOG2E, -mm));
            s += exp2f(fmaf(acc[mt][1][j], LOG2E, -mm));
            s += exp2f(fmaf(acc[mt][2][j], LOG2E, -mm));
            s += exp2f(fmaf(acc[mt][3][j], LOG2E, -mm));
#pragma unroll
            for (int off = 1; off < 16; off <<= 1)
                s += __shfl_xor(s, off, 16);
            if (lrow == 0) {
                int row = mt * 16 + (lane >> 4) * 4 + j;
                partm[wave][row] = m;
                parts[wave][row] = s;
            }
        }
    }
    __syncthreads();
    if (tid < 64) {
        float m = partm[0][tid];
        float s = parts[0][tid];
#pragma unroll
        for (int w = 1; w < 16; w++) {
            float mo = partm[w][tid], so = parts[w][tid];
            float M = fmaxf(m, mo);
            s = s * __expf(m - M) + so * __expf(mo - M);
            m = M;
        }
        lse_sh[tid] = m + __logf(s);
    }
    __syncthreads();

    // Write blank (col 0) and emit (target col) into skewed layout
#pragma unroll
    for (int mt = 0; mt < 4; mt++) {
#pragma unroll
        for (int j = 0; j < 4; j++) {
            int lr = mt * 16 + (lane >> 4) * 4 + j;
            int r = r0 + lr;
            if (r >= M_TOT) continue;
            int tc = tgt_sh[lr];
            bool isblank = (wave == 0) && (lrow == 0);
            bool isemit = (tc >= 0) && ((tc >> 6) == wave) && ((tc & 15) == lrow);
            if (isblank || isemit) {
                int b = r / 20200;
                int rem = r - b * 20200;
                int t = rem / 101;
                int u = rem - t * 101;
                float lse = lse_sh[lr];
                if (isblank)
                    bsk[(b * NDIAG + t + u) * DSTR + u] = acc[mt][0][j] - lse;
                if (isemit) {
                    int ntl = (tc >> 4) & 3;
                    float v = acc[mt][0][j];
#pragma unroll
                    for (int nt = 1; nt < 4; nt++)
                        if (nt == ntl) v = acc[mt][nt][j];
                    esk[(b * NDIAG + t + u) * DSTR + u] = v - lse;
                }
            }
        }
    }
}

// ---------------------------------------------------------------------------
// Alpha recursion: one wave per batch, barrier-free, 4-deep prefetch ring.
// Lane l holds u1=l and u2=64+l. u-1 deps via shfl_up(1) + lane-63 seam.
// ---------------------------------------------------------------------------
__global__ __launch_bounds__(256) void alpha4_kernel(
    const float* __restrict__ bsk, const float* __restrict__ esk,
    const int* __restrict__ enc_len, const int* __restrict__ tgt_len,
    float* __restrict__ out) {
    __shared__ float ll_sh[B_];
    const int tid = threadIdx.x;
    const int b = tid >> 6;
    const int l = tid & 63;
    const float* Bp = bsk + b * (NDIAG * DSTR);
    const float* Ep = esk + b * (NDIAG * DSTR);
    const int el = enc_len[b];
    const int tl = tgt_len[b];
    const int dfin = el - 1 + tl;

    float a1 = (l == 0) ? 0.0f : -INFINITY;
    float a2 = -INFINITY;

    // ring slots k hold rows (advancing); init rows 0..3
    float rb1[4], rb2[4], re1[4], re2[4];
#pragma unroll
    for (int k = 0; k < 4; k++) {
        rb1[k] = Bp[k * DSTR + l];
        rb2[k] = Bp[k * DSTR + 64 + l];
        re1[k] = Ep[k * DSTR + l];
        re2[k] = Ep[k * DSTR + 64 + l];
    }

    for (int dc = 1; dc <= 297; dc += 4) {
#pragma unroll
        for (int q = 0; q < 4; q++) {
            const int d = dc + q;       // 1..300
            if (d > NDIAG - 1) continue;
            const int sc = (d - 1) & 3;
            const int sm = d & 3;
            // consume
            float cb1 = rb1[sc], cb2 = rb2[sc], ce1 = re1[sc], ce2 = re2[sc];
            float mb1 = rb1[sm], mb2 = rb2[sm];
            // prefetch row d+3 into freed slot
            int dn = d + 3;
            if (dn > NDIAG - 1) dn = NDIAG - 1;
            rb1[sc] = Bp[dn * DSTR + l];
            rb2[sc] = Bp[dn * DSTR + 64 + l];
            re1[sc] = Ep[dn * DSTR + l];
            re2[sc] = Ep[dn * DSTR + 64 + l];

            float pe1 = __shfl_up(ce1, 1, 64);
            float e1hi = __shfl(ce1, 63, 64);
            float pe2s = __shfl_up(ce2, 1, 64);
            float pe2 = (l == 0) ? e1hi : pe2s;
            float pa1 = __shfl_up(a1, 1, 64);
            float a1hi = __shfl(a1, 63, 64);
            float pa2s = __shfl_up(a2, 1, 64);
            float pa2 = (l == 0) ? a1hi : pa2s;

            const int t1 = d - l;
            float va = a1 + cb1;
            float vb = (l >= 1) ? pa1 + pe1 : -INFINITY;
            float M = fmaxf(va, vb);
            float v1 = (M == -INFINITY)
                           ? -INFINITY
                           : M + __logf(1.0f + __expf(fminf(va, vb) - M));
            if (t1 < 0 || t1 >= T_ || l > U_) v1 = -INFINITY;

            const int t2 = d - 64 - l;
            float va2 = a2 + cb2;
            float vb2 = pa2 + pe2;
            float M2 = fmaxf(va2, vb2);
            float v2 = (M2 == -INFINITY)
                           ? -INFINITY
                           : M2 + __logf(1.0f + __expf(fminf(va2, vb2) - M2));
            if (t2 < 0 || t2 >= T_ || (64 + l) > U_) v2 = -INFINITY;

            if (d == dfin) {
                if (l == tl) ll_sh[b] = v1 + mb1;
                if (64 + l == tl) ll_sh[b] = v2 + mb2;
            }
            a1 = v1;
            a2 = v2;
        }
    }
    __syncthreads();
    if (tid == 0)
        out[0] = -0.25f * (ll_sh[0] + ll_sh[1] + ll_sh[2] + ll_sh[3]);
}

extern "C" void kernel_launch(void* const* d_in, const int* in_sizes, int n_in,
                              void* d_out, int out_size, void* d_ws, size_t ws_size,
                              hipStream_t stream) {
    const float* enc_out = (const float*)d_in[0];
    const float* dec_out = (const float*)d_in[1];
    const float* W_enc = (const float*)d_in[2];
    const float* b_enc = (const float*)d_in[3];
    const float* W_dec = (const float*)d_in[4];
    const float* b_dec = (const float*)d_in[5];
    const float* W_out = (const float*)d_in[6];
    const float* b_out = (const float*)d_in[7];
    const int* targets = (const int*)d_in[8];
    const int* enc_len = (const int*)d_in[9];
    const int* tgt_len = (const int*)d_in[10];

    float* ws = (float*)d_ws;
    float* enc_p = ws;                          // B*T*J      = 256000 f32
    float* dec_p = enc_p + B_ * T_ * J_;        // B*101*J    = 129280 f32
    float* bsk = dec_p + B_ * (U_ + 1) * J_;    // 4*300*104  = 124800 f32
    float* esk = bsk + B_ * NDIAG * DSTR;       // 4*300*104  = 124800 f32
    ushort* Wt = (ushort*)(esk + B_ * NDIAG * DSTR);  // 327680 bf16

    prep_kernel<<<2228, 320, 0, stream>>>(enc_out, dec_out, W_enc, b_enc,
                                          W_dec, b_dec, W_out, enc_p, dec_p, Wt);

    joint_mfma<<<(M_TOT + 63) / 64, 1024, 0, stream>>>(
        enc_p, dec_p, Wt, b_out, targets, bsk, esk);

    alpha4_kernel<<<1, 256, 0, stream>>>(bsk, esk, enc_len, tgt_len, (float*)d_out);
}